// Round 17
// baseline (587.978 us; speedup 1.0000x reference)
//
#include <hip/hip_runtime.h>
#include <hip/hip_bf16.h>
#include <cstdint>

#define AS_GLOBAL __attribute__((address_space(1)))
#define AS_LDS    __attribute__((address_space(3)))

typedef __attribute__((ext_vector_type(8))) short bf16x8;
typedef __attribute__((ext_vector_type(8))) unsigned short u16x8;
typedef __attribute__((ext_vector_type(4))) float f32x4;

static __device__ __forceinline__ ushort f2bf(float x) {
    union { float f; uint32_t u; } c;
    c.f = x;
    uint32_t u = c.u;
    u += 0x7fffu + ((u >> 16) & 1u);   // RTNE
    return (ushort)(u >> 16);
}
static __device__ __forceinline__ float bf2f(ushort u) {
    union { uint32_t i; float f; } c;
    c.i = ((uint32_t)u) << 16;
    return c.f;
}

// async global->LDS, 16B/lane. Dest = wave-uniform base + lane*16.
static __device__ __forceinline__ void gload_lds16(const void* g, void* l) {
    __builtin_amdgcn_global_load_lds(
        (const AS_GLOBAL uint32_t*)(uintptr_t)g,
        (AS_LDS uint32_t*)(uint32_t)(uintptr_t)l,
        16, 0, 0);
}

// ---------------- fp32 -> bf16 convert (one tensor per dispatch; L3-friendly) ----------------
__global__ __launch_bounds__(256)
void cvt_f32_bf16(const float4* __restrict__ in, u16x8* __restrict__ out, int n8) {
    int i = blockIdx.x * 256 + threadIdx.x;
    int stride = gridDim.x * 256;
    for (; i < n8; i += stride) {
        float4 a = in[i * 2], b = in[i * 2 + 1];
        u16x8 o;
        o[0] = f2bf(a.x); o[1] = f2bf(a.y); o[2] = f2bf(a.z); o[3] = f2bf(a.w);
        o[4] = f2bf(b.x); o[5] = f2bf(b.y); o[6] = f2bf(b.z); o[7] = f2bf(b.w);
        out[i] = o;
    }
}

// ---------------- [K,N] fp32 -> [N,K] bf16 transpose (4 weights, z-indexed) ----------------
__global__ __launch_bounds__(256)
void transpose4_to_bf16(const float* __restrict__ w0, const float* __restrict__ w1,
                        const float* __restrict__ w2, const float* __restrict__ w3,
                        ushort* __restrict__ t0, ushort* __restrict__ t1,
                        ushort* __restrict__ t2, ushort* __restrict__ t3) {
    const int K = 1024, N = 1024;
    __shared__ float tile[32][33];
    const float* w; ushort* wt;
    switch (blockIdx.z) {
        case 0: w = w0; wt = t0; break;
        case 1: w = w1; wt = t1; break;
        case 2: w = w2; wt = t2; break;
        default: w = w3; wt = t3; break;
    }
    int bn = blockIdx.x * 32;
    int bk = blockIdx.y * 32;
    int tx = threadIdx.x & 31, ty = threadIdx.x >> 5;
    #pragma unroll
    for (int i = 0; i < 32; i += 8)
        tile[ty + i][tx] = w[(size_t)(bk + ty + i) * N + bn + tx];
    __syncthreads();
    #pragma unroll
    for (int i = 0; i < 32; i += 8)
        wt[(size_t)(bn + ty + i) * K + bk + tx] = f2bf(tile[tx][ty + i]);
}

// =====================================================================
// 8-phase snake GEMM (r16-proven structure, best measured) + fused
// per-chunk partial sums in the epilogue.
// PART: 0 = none; 1 = write pke partials (sum of C values, bf16-rounded);
//       2 = write pkv partials (sum of keb[idx]*C, both bf16-rounded).
// Partials layout [chunk][b*H+h]; each (chunk, 16-col group) is produced
// by exactly one block (chunk rows within one M-tile, cols within one
// N-tile) -> plain stores, no atomics.  Chunk = frag-pair (2p,2p+1):
// rows m0+wr*128+{0,32,64,96}+0..31 (verified against C/D layout).
// C[M,1024] = A[M,1024](bf16) * Bt[1024,1024](bf16).
// EPI: 0=none 1=sigmoid 2=exp.  OUT_BF: bf16 C.
// =====================================================================
template<int EPI, int OUT_BF, int PART>
__global__ __launch_bounds__(512, 2)
void gemm8p(const ushort* __restrict__ A, const ushort* __restrict__ Bt,
            void* __restrict__ Cv, const ushort* __restrict__ ke_in,
            float* __restrict__ part_out) {
    constexpr int K = 1024, N = 1024;
    __shared__ alignas(16) ushort sA[2][16384];   // halves: [mh][rl 0..127][8 slots]
    __shared__ alignas(16) ushort sB[2][16384];   // halves: [nh][cl 0..127][8 slots]
    const int tid  = threadIdx.x;
    const int wid  = tid >> 6;
    const int lane = tid & 63;
    const int wr = wid >> 2, wc = wid & 3;        // 2M x 4N waves, 128x64 each
    const int lr = lane & 15;
    const int kb = lane >> 4;                     // 0..3
    const int x7 = lr & 7;                        // read-side XOR (row&7 == lr&7)

    // XCD swizzle: 512 wgs = 8 xcds x 64 locals; M panels 128 = 8 x 16.
    const int wg = blockIdx.x;
    const int xcd = wg & 7, local = wg >> 3;
    const int bm = xcd * 16 + (local >> 2);
    const int bn = local & 3;
    const int m0 = bm * 256, n0 = bn * 256;

    f32x4 acc[8][4] = {};                         // [mq*4+m][nq*2+n]
    bf16x8 af[4][2];                              // SINGLE A frag set
    bf16x8 bv[2][2];                              // SINGLE B frag set

    auto stageA = [&](int tile, int buf, int mh) {
        const int kt0 = tile * 64;
        #pragma unroll
        for (int j = 0; j < 2; j++) {
            int c = j * 512 + tid;                // 0..1023
            int rl = c >> 3, p = c & 7;
            int s = p ^ (rl & 7);
            int gr = (rl >> 6) * 128 + mh * 64 + (rl & 63);
            gload_lds16(A + (size_t)(m0 + gr) * K + kt0 + s * 8,
                        &sA[buf][mh * 8192 + c * 8]);
        }
    };
    auto stageB = [&](int tile, int buf, int nh) {
        const int kt0 = tile * 64;
        #pragma unroll
        for (int j = 0; j < 2; j++) {
            int c = j * 512 + tid;
            int cl = c >> 3, p = c & 7;
            int s = p ^ (cl & 7);
            int gc = (cl >> 5) * 64 + nh * 32 + (cl & 31);
            gload_lds16(Bt + (size_t)(n0 + gc) * K + kt0 + s * 8,
                        &sB[buf][nh * 8192 + c * 8]);
        }
    };
    auto readA = [&](int buf, int mq) {
        #pragma unroll
        for (int m = 0; m < 4; m++)
            #pragma unroll
            for (int kh = 0; kh < 2; kh++)
                af[m][kh] = *(const bf16x8*)&sA[buf][mq * 8192
                              + (wr * 64 + m * 16 + lr) * 64
                              + ((kh * 4 + kb) ^ x7) * 8];
    };
    auto readB = [&](int buf, int nq) {
        #pragma unroll
        for (int n = 0; n < 2; n++)
            #pragma unroll
            for (int kh = 0; kh < 2; kh++)
                bv[n][kh] = *(const bf16x8*)&sB[buf][nq * 8192
                              + (wc * 32 + n * 16 + lr) * 64
                              + ((kh * 4 + kb) ^ x7) * 8];
    };
    auto mfma16 = [&](int mq, int nq) {
        #pragma unroll
        for (int m = 0; m < 4; m++)
            #pragma unroll
            for (int n = 0; n < 2; n++) {
                acc[mq*4+m][nq*2+n] = __builtin_amdgcn_mfma_f32_16x16x32_bf16(
                    af[m][0], bv[n][0], acc[mq*4+m][nq*2+n], 0, 0, 0);
                acc[mq*4+m][nq*2+n] = __builtin_amdgcn_mfma_f32_16x16x32_bf16(
                    af[m][1], bv[n][1], acc[mq*4+m][nq*2+n], 0, 0, 0);
            }
    };

// phase: [frag reads] [stage] barrier; lgkmcnt(0); setprio MFMA; [end-wait]; barrier
#define PHASE(MQ, NQ, READS, STAGES, ENDW) { \
    READS \
    STAGES \
    asm volatile("" ::: "memory"); \
    __builtin_amdgcn_s_barrier(); \
    asm volatile("s_waitcnt lgkmcnt(0)" ::: "memory"); \
    __builtin_amdgcn_s_setprio(1); \
    mfma16(MQ, NQ); \
    __builtin_amdgcn_s_setprio(0); \
    ENDW \
    asm volatile("" ::: "memory"); \
    __builtin_amdgcn_s_barrier(); \
    asm volatile("" ::: "memory"); \
}

    // ---- prologue: stage tiles 0,1 fully; drain ----
    stageA(0, 0, 0); stageA(0, 0, 1); stageB(0, 0, 0); stageB(0, 0, 1);
    stageA(1, 1, 0); stageA(1, 1, 1); stageB(1, 1, 0); stageB(1, 1, 1);
    asm volatile("s_waitcnt vmcnt(0)" ::: "memory");
    __builtin_amdgcn_s_barrier();
    asm volatile("" ::: "memory");

    // ---- main loop: 8 iterations x 2 K-tiles; snake reads + derived waits ----
    for (int i = 0; i < 8; i++) {
        const int t = 2 * i;
        const int bt = t & 1, bt1 = bt ^ 1;
        PHASE(0, 0,
            { readA(bt, 0); readB(bt, 0); },
            { if (i > 0) stageA(t + 1, bt1, 0); },
            { asm volatile("s_waitcnt vmcnt(6)" ::: "memory"); })
        PHASE(1, 0,
            { readA(bt, 1); },
            { if (i > 0) stageA(t + 1, bt1, 1); },
            { })
        PHASE(1, 1,
            { readB(bt, 1); },
            { if (i < 7) stageB(t + 2, bt, 0); },
            { })
        PHASE(0, 1,
            { readA(bt, 0); },
            { if (i < 7) stageB(t + 2, bt, 1); },
            { if (i < 7) asm volatile("s_waitcnt vmcnt(6)" ::: "memory");
              else       asm volatile("s_waitcnt vmcnt(0)" ::: "memory"); })
        PHASE(0, 0,
            { readA(bt1, 0); readB(bt1, 0); },
            { if (i < 7) stageA(t + 2, bt, 0); },
            { asm volatile("s_waitcnt vmcnt(6)" ::: "memory"); })
        PHASE(1, 0,
            { readA(bt1, 1); },
            { if (i < 7) stageA(t + 2, bt, 1); },
            { })
        PHASE(1, 1,
            { readB(bt1, 1); },
            { if (i < 7) stageB(t + 3, bt1, 0); },
            { })
        PHASE(0, 1,
            { readA(bt1, 0); },
            { if (i < 7) stageB(t + 3, bt1, 1); },
            { if (i < 7) asm volatile("s_waitcnt vmcnt(6)" ::: "memory"); })
    }
#undef PHASE

    // ---- epilogue (C/D: col=lane&15, row=(lane>>4)*4+r) ----
    float*  Cf = (float*)Cv;
    ushort* Cb = (ushort*)Cv;
    if (PART == 0) {
        #pragma unroll
        for (int am = 0; am < 8; am++) {
            #pragma unroll
            for (int an = 0; an < 4; an++) {
                #pragma unroll
                for (int r = 0; r < 4; r++) {
                    int row = m0 + wr * 128 + (am >> 2) * 64 + (am & 3) * 16 + (lane >> 4) * 4 + r;
                    int col = n0 + wc * 64 + (an >> 1) * 32 + (an & 1) * 16 + lr;
                    float v = acc[am][an][r];
                    if (EPI == 1) v = 1.0f / (1.0f + __expf(-v));
                    else if (EPI == 2) v = __expf(v);
                    size_t idx = (size_t)row * N + col;
                    if (OUT_BF) Cb[idx] = f2bf(v);
                    else        Cf[idx] = v;
                }
            }
        }
    } else {
        // C-write + fused per-chunk column partial sums.
        #pragma unroll
        for (int an = 0; an < 4; an++) {
            const int col = n0 + wc * 64 + (an >> 1) * 32 + (an & 1) * 16 + lr;
            #pragma unroll
            for (int ap = 0; ap < 4; ap++) {          // frag pair (2ap, 2ap+1) = one 32-row chunk
                float csum = 0.f;
                #pragma unroll
                for (int h = 0; h < 2; h++) {
                    const int am = ap * 2 + h;
                    const int rbase = m0 + wr * 128 + (am >> 2) * 64 + (am & 3) * 16 + (lane >> 4) * 4;
                    #pragma unroll
                    for (int r = 0; r < 4; r++) {
                        float v = acc[am][an][r];
                        if (EPI == 2) v = __expf(v);
                        ushort vb = f2bf(v);
                        size_t idx = (size_t)(rbase + r) * N + col;
                        Cb[idx] = vb;
                        float vr = bf2f(vb);          // bf16-rounded, matches scan inputs
                        if (PART == 1) csum += vr;
                        else           csum += bf2f(ke_in[idx]) * vr;
                    }
                }
                csum += __shfl_xor(csum, 16, 64);
                csum += __shfl_xor(csum, 32, 64);
                if ((lane >> 4) == 0) {
                    const int row0 = m0 + wr * 128 + ((ap * 2) >> 2) * 64 + ((ap * 2) & 3) * 16;
                    const int bb = row0 >> 13;        // row / 8192
                    const int cc = (row0 & 8191) >> 5; // chunk within batch
                    part_out[(size_t)cc * 4096 + bb * 1024 + col] = csum;
                }
            }
        }
    }
}

// ---------------- scan pass B: exclusive prefix over chunks ----------------
__global__ __launch_bounds__(256)
void scan_offsets(float* __restrict__ pke, float* __restrict__ pkv, int nch, int BH) {
    int i = blockIdx.x * blockDim.x + threadIdx.x;
    if (i >= BH) return;
    float rke = 0.f, rkv = 0.f;
    #pragma unroll 8
    for (int c = 0; c < nch; c++) {
        size_t idx = (size_t)c * BH + i;
        float a = pke[idx], b = pkv[idx];
        pke[idx] = rke; pkv[idx] = rkv;
        rke += a; rkv += b;
    }
}

// ---------------- scan pass C: inclusive scan + y = sigmoid(emb_q)*(kv/ke) ----------------
__global__ __launch_bounds__(256)
void scan_final(const ushort* __restrict__ ke, const ushort* __restrict__ ev,
                const ushort* __restrict__ sq,
                const float* __restrict__ pke, const float* __restrict__ pkv,
                ushort* __restrict__ ybf) {
    const int H = 1024, S = 8192, CHUNK = 32, BH = 4096;
    int c  = blockIdx.x * 2 + (threadIdx.x >> 7);
    int h0 = (threadIdx.x & 127) * 8;
    int b  = blockIdx.y;
    size_t p = (size_t)c * BH + b * H + h0;
    float rke[8], rkv[8];
    *(float4*)(rke)     = *(const float4*)(pke + p);
    *(float4*)(rke + 4) = *(const float4*)(pke + p + 4);
    *(float4*)(rkv)     = *(const float4*)(pkv + p);
    *(float4*)(rkv + 4) = *(const float4*)(pkv + p + 4);
    size_t base = ((size_t)b * S + (size_t)c * CHUNK) * H + h0;
    for (int s = 0; s < CHUNK; s++) {
        size_t idx = base + (size_t)s * H;
        u16x8 e8 = *(const u16x8*)(ke + idx);
        u16x8 v8 = *(const u16x8*)(ev + idx);
        u16x8 q8 = *(const u16x8*)(sq + idx);
        u16x8 o;
        #pragma unroll
        for (int i = 0; i < 8; i++) {
            float e = bf2f(e8[i]);
            rke[i] += e;
            rkv[i] += e * bf2f(v8[i]);
            o[i] = f2bf(bf2f(q8[i]) * (rkv[i] / rke[i]));
        }
        *(u16x8*)(ybf + idx) = o;
    }
}

extern "C" void kernel_launch(void* const* d_in, const int* in_sizes, int n_in,
                              void* d_out, int out_size, void* d_ws, size_t ws_size,
                              hipStream_t stream) {
    const float* q   = (const float*)d_in[0];
    const float* k   = (const float*)d_in[1];
    const float* v   = (const float*)d_in[2];
    const float* w_q = (const float*)d_in[3];
    const float* w_k = (const float*)d_in[4];
    const float* w_v = (const float*)d_in[5];
    const float* w_p = (const float*)d_in[6];
    float* out = (float*)d_out;

    const int B = 4, S = 8192, H = 1024;
    const int M = B * S;                  // 32768
    const size_t MH = (size_t)M * H;      // 33,554,432
    const int NCH = 256;                  // CHUNK = 32
    const int BH = B * H;                 // 4096

    char* ws = (char*)d_ws;
    size_t off = 0;
    auto alloc = [&](size_t bytes) -> char* {
        char* p = ws + off;
        off += (bytes + 255) & ~(size_t)255;
        return p;
    };
    ushort* abuf = (ushort*)alloc(MH * 2);     // bf16 staging for q/k/v/y (reused serially)
    ushort* wqt  = (ushort*)alloc((size_t)H * H * 2);
    ushort* wkt  = (ushort*)alloc((size_t)H * H * 2);
    ushort* wvt  = (ushort*)alloc((size_t)H * H * 2);
    ushort* wpt  = (ushort*)alloc((size_t)H * H * 2);
    ushort* sqb  = (ushort*)alloc(MH * 2);
    ushort* keb  = (ushort*)alloc(MH * 2);
    ushort* evb  = (ushort*)alloc(MH * 2);
    float*  pke  = (float*)alloc((size_t)NCH * BH * 4);
    float*  pkv  = (float*)alloc((size_t)NCH * BH * 4);

    const int ngg = (M / 256) * (H / 256);   // 512 blocks, swizzled in-kernel
    dim3 tg(H / 32, H / 32, 4);
    dim3 gs(NCH / 2, B);
    const int n8 = (int)(MH / 8);

    transpose4_to_bf16<<<tg, 256, 0, stream>>>(w_q, w_k, w_v, w_p, wqt, wkt, wvt, wpt);

    // sq = sigmoid(q @ w_q)
    cvt_f32_bf16<<<2048, 256, 0, stream>>>((const float4*)q, (u16x8*)abuf, n8);
    gemm8p<1, 1, 0><<<ngg, 512, 0, stream>>>(abuf, wqt, sqb, nullptr, nullptr);
    // ke = exp(k @ w_k)  + fused pke chunk partials
    cvt_f32_bf16<<<2048, 256, 0, stream>>>((const float4*)k, (u16x8*)abuf, n8);
    gemm8p<2, 1, 1><<<ngg, 512, 0, stream>>>(abuf, wkt, keb, nullptr, pke);
    // ev = v @ w_v  + fused pkv chunk partials (reads keb)
    cvt_f32_bf16<<<2048, 256, 0, stream>>>((const float4*)v, (u16x8*)abuf, n8);
    gemm8p<0, 1, 2><<<ngg, 512, 0, stream>>>(abuf, wvt, evb, keb, pkv);

    // hierarchical scan over S (partials already computed in GEMM epilogues)
    scan_offsets<<<BH / 256, 256, 0, stream>>>(pke, pkv, NCH, BH);
    scan_final<<<gs, 256, 0, stream>>>(keb, evb, sqb, pke, pkv, abuf);

    // out = y @ w_p (fp32 out)
    gemm8p<0, 0, 0><<<ngg, 512, 0, stream>>>(abuf, wpt, out, nullptr, nullptr);
}

// Round 18
// 515.274 us; speedup vs baseline: 1.1411x; 1.1411x over previous
//
#include <hip/hip_runtime.h>
#include <hip/hip_bf16.h>
#include <cstdint>

#define AS_GLOBAL __attribute__((address_space(1)))
#define AS_LDS    __attribute__((address_space(3)))

typedef __attribute__((ext_vector_type(8))) short bf16x8;
typedef __attribute__((ext_vector_type(8))) unsigned short u16x8;
typedef __attribute__((ext_vector_type(4))) float f32x4;

static __device__ __forceinline__ ushort f2bf(float x) {
    union { float f; uint32_t u; } c;
    c.f = x;
    uint32_t u = c.u;
    u += 0x7fffu + ((u >> 16) & 1u);   // RTNE
    return (ushort)(u >> 16);
}
static __device__ __forceinline__ float bf2f(ushort u) {
    union { uint32_t i; float f; } c;
    c.i = ((uint32_t)u) << 16;
    return c.f;
}

// async global->LDS, 16B/lane. Dest = wave-uniform base + lane*16.
static __device__ __forceinline__ void gload_lds16(const void* g, void* l) {
    __builtin_amdgcn_global_load_lds(
        (const AS_GLOBAL uint32_t*)(uintptr_t)g,
        (AS_LDS uint32_t*)(uint32_t)(uintptr_t)l,
        16, 0, 0);
}

// ---------------- fp32 -> bf16 convert (one tensor per dispatch; L3-friendly) ----------------
__global__ __launch_bounds__(256)
void cvt_f32_bf16(const float4* __restrict__ in, u16x8* __restrict__ out, int n8) {
    int i = blockIdx.x * 256 + threadIdx.x;
    int stride = gridDim.x * 256;
    for (; i < n8; i += stride) {
        float4 a = in[i * 2], b = in[i * 2 + 1];
        u16x8 o;
        o[0] = f2bf(a.x); o[1] = f2bf(a.y); o[2] = f2bf(a.z); o[3] = f2bf(a.w);
        o[4] = f2bf(b.x); o[5] = f2bf(b.y); o[6] = f2bf(b.z); o[7] = f2bf(b.w);
        out[i] = o;
    }
}

// ---------------- [K,N] fp32 -> [N,K] bf16 transpose (4 weights, z-indexed) ----------------
__global__ __launch_bounds__(256)
void transpose4_to_bf16(const float* __restrict__ w0, const float* __restrict__ w1,
                        const float* __restrict__ w2, const float* __restrict__ w3,
                        ushort* __restrict__ t0, ushort* __restrict__ t1,
                        ushort* __restrict__ t2, ushort* __restrict__ t3) {
    const int K = 1024, N = 1024;
    __shared__ float tile[32][33];
    const float* w; ushort* wt;
    switch (blockIdx.z) {
        case 0: w = w0; wt = t0; break;
        case 1: w = w1; wt = t1; break;
        case 2: w = w2; wt = t2; break;
        default: w = w3; wt = t3; break;
    }
    int bn = blockIdx.x * 32;
    int bk = blockIdx.y * 32;
    int tx = threadIdx.x & 31, ty = threadIdx.x >> 5;
    #pragma unroll
    for (int i = 0; i < 32; i += 8)
        tile[ty + i][tx] = w[(size_t)(bk + ty + i) * N + bn + tx];
    __syncthreads();
    #pragma unroll
    for (int i = 0; i < 32; i += 8)
        wt[(size_t)(bn + ty + i) * K + bk + tx] = f2bf(tile[tx][ty + i]);
}

// =====================================================================
// 8-phase GEMM (snake order): 256x256 tile, BK=64, 8 waves (2M x 4N),
// wave tile 128x64, 2-buffer LDS (128KB, 1 block/CU).  Snake quadrant
// order (M0,N0)->(M1,N0)->(M1,N1)->(M0,N1): one operand set changes per
// phase -> ONE af + ONE bv set.  FIFO-simulated counted waits: vmcnt(6)
// at ends of p0,p3,p4,p7.  Best measured GEMM (r16: 507.4 µs total).
// C[M,1024] = A[M,1024](bf16) * Bt[1024,1024](bf16).
// EPI: 0=none 1=sigmoid 2=exp.  OUT_BF: bf16 C.
// =====================================================================
template<int EPI, int OUT_BF>
__global__ __launch_bounds__(512, 2)
void gemm8p(const ushort* __restrict__ A, const ushort* __restrict__ Bt,
            void* __restrict__ Cv) {
    constexpr int K = 1024, N = 1024;
    __shared__ alignas(16) ushort sA[2][16384];   // halves: [mh][rl 0..127][8 slots]
    __shared__ alignas(16) ushort sB[2][16384];   // halves: [nh][cl 0..127][8 slots]
    const int tid  = threadIdx.x;
    const int wid  = tid >> 6;
    const int lane = tid & 63;
    const int wr = wid >> 2, wc = wid & 3;        // 2M x 4N waves, 128x64 each
    const int lr = lane & 15;
    const int kb = lane >> 4;                     // 0..3
    const int x7 = lr & 7;                        // read-side XOR (row&7 == lr&7)

    // XCD swizzle: 512 wgs = 8 xcds x 64 locals; M panels 128 = 8 x 16.
    const int wg = blockIdx.x;
    const int xcd = wg & 7, local = wg >> 3;
    const int bm = xcd * 16 + (local >> 2);
    const int bn = local & 3;
    const int m0 = bm * 256, n0 = bn * 256;

    f32x4 acc[8][4] = {};                         // [mq*4+m][nq*2+n]
    bf16x8 af[4][2];                              // SINGLE A frag set
    bf16x8 bv[2][2];                              // SINGLE B frag set

    auto stageA = [&](int tile, int buf, int mh) {
        const int kt0 = tile * 64;
        #pragma unroll
        for (int j = 0; j < 2; j++) {
            int c = j * 512 + tid;                // 0..1023
            int rl = c >> 3, p = c & 7;
            int s = p ^ (rl & 7);
            int gr = (rl >> 6) * 128 + mh * 64 + (rl & 63);
            gload_lds16(A + (size_t)(m0 + gr) * K + kt0 + s * 8,
                        &sA[buf][mh * 8192 + c * 8]);
        }
    };
    auto stageB = [&](int tile, int buf, int nh) {
        const int kt0 = tile * 64;
        #pragma unroll
        for (int j = 0; j < 2; j++) {
            int c = j * 512 + tid;
            int cl = c >> 3, p = c & 7;
            int s = p ^ (cl & 7);
            int gc = (cl >> 5) * 64 + nh * 32 + (cl & 31);
            gload_lds16(Bt + (size_t)(n0 + gc) * K + kt0 + s * 8,
                        &sB[buf][nh * 8192 + c * 8]);
        }
    };
    auto readA = [&](int buf, int mq) {
        #pragma unroll
        for (int m = 0; m < 4; m++)
            #pragma unroll
            for (int kh = 0; kh < 2; kh++)
                af[m][kh] = *(const bf16x8*)&sA[buf][mq * 8192
                              + (wr * 64 + m * 16 + lr) * 64
                              + ((kh * 4 + kb) ^ x7) * 8];
    };
    auto readB = [&](int buf, int nq) {
        #pragma unroll
        for (int n = 0; n < 2; n++)
            #pragma unroll
            for (int kh = 0; kh < 2; kh++)
                bv[n][kh] = *(const bf16x8*)&sB[buf][nq * 8192
                              + (wc * 32 + n * 16 + lr) * 64
                              + ((kh * 4 + kb) ^ x7) * 8];
    };
    auto mfma16 = [&](int mq, int nq) {
        #pragma unroll
        for (int m = 0; m < 4; m++)
            #pragma unroll
            for (int n = 0; n < 2; n++) {
                acc[mq*4+m][nq*2+n] = __builtin_amdgcn_mfma_f32_16x16x32_bf16(
                    af[m][0], bv[n][0], acc[mq*4+m][nq*2+n], 0, 0, 0);
                acc[mq*4+m][nq*2+n] = __builtin_amdgcn_mfma_f32_16x16x32_bf16(
                    af[m][1], bv[n][1], acc[mq*4+m][nq*2+n], 0, 0, 0);
            }
    };

// phase: [frag reads] [stage] barrier; lgkmcnt(0); setprio MFMA; [end-wait]; barrier
#define PHASE(MQ, NQ, READS, STAGES, ENDW) { \
    READS \
    STAGES \
    asm volatile("" ::: "memory"); \
    __builtin_amdgcn_s_barrier(); \
    asm volatile("s_waitcnt lgkmcnt(0)" ::: "memory"); \
    __builtin_amdgcn_s_setprio(1); \
    mfma16(MQ, NQ); \
    __builtin_amdgcn_s_setprio(0); \
    ENDW \
    asm volatile("" ::: "memory"); \
    __builtin_amdgcn_s_barrier(); \
    asm volatile("" ::: "memory"); \
}

    // ---- prologue: stage tiles 0,1 fully; drain ----
    stageA(0, 0, 0); stageA(0, 0, 1); stageB(0, 0, 0); stageB(0, 0, 1);
    stageA(1, 1, 0); stageA(1, 1, 1); stageB(1, 1, 0); stageB(1, 1, 1);
    asm volatile("s_waitcnt vmcnt(0)" ::: "memory");
    __builtin_amdgcn_s_barrier();
    asm volatile("" ::: "memory");

    // ---- main loop: 8 iterations x 2 K-tiles; snake reads + derived waits ----
    for (int i = 0; i < 8; i++) {
        const int t = 2 * i;
        const int bt = t & 1, bt1 = bt ^ 1;
        PHASE(0, 0,
            { readA(bt, 0); readB(bt, 0); },
            { if (i > 0) stageA(t + 1, bt1, 0); },
            { asm volatile("s_waitcnt vmcnt(6)" ::: "memory"); })
        PHASE(1, 0,
            { readA(bt, 1); },
            { if (i > 0) stageA(t + 1, bt1, 1); },
            { })
        PHASE(1, 1,
            { readB(bt, 1); },
            { if (i < 7) stageB(t + 2, bt, 0); },
            { })
        PHASE(0, 1,
            { readA(bt, 0); },
            { if (i < 7) stageB(t + 2, bt, 1); },
            { if (i < 7) asm volatile("s_waitcnt vmcnt(6)" ::: "memory");
              else       asm volatile("s_waitcnt vmcnt(0)" ::: "memory"); })
        PHASE(0, 0,
            { readA(bt1, 0); readB(bt1, 0); },
            { if (i < 7) stageA(t + 2, bt, 0); },
            { asm volatile("s_waitcnt vmcnt(6)" ::: "memory"); })
        PHASE(1, 0,
            { readA(bt1, 1); },
            { if (i < 7) stageA(t + 2, bt, 1); },
            { })
        PHASE(1, 1,
            { readB(bt1, 1); },
            { if (i < 7) stageB(t + 3, bt1, 0); },
            { })
        PHASE(0, 1,
            { readA(bt1, 0); },
            { if (i < 7) stageB(t + 3, bt1, 1); },
            { if (i < 7) asm volatile("s_waitcnt vmcnt(6)" ::: "memory"); })
    }
#undef PHASE

    // ---- epilogue (C/D: col=lane&15, row=(lane>>4)*4+r) ----
    float*  Cf = (float*)Cv;
    ushort* Cb = (ushort*)Cv;
    #pragma unroll
    for (int am = 0; am < 8; am++) {
        #pragma unroll
        for (int an = 0; an < 4; an++) {
            #pragma unroll
            for (int r = 0; r < 4; r++) {
                int row = m0 + wr * 128 + (am >> 2) * 64 + (am & 3) * 16 + (lane >> 4) * 4 + r;
                int col = n0 + wc * 64 + (an >> 1) * 32 + (an & 1) * 16 + lr;
                float v = acc[am][an][r];
                if (EPI == 1) v = 1.0f / (1.0f + __expf(-v));
                else if (EPI == 2) v = __expf(v);
                size_t idx = (size_t)row * N + col;
                if (OUT_BF) Cb[idx] = f2bf(v);
                else        Cf[idx] = v;
            }
        }
    }
}

// ---------------- scan pass A: per-chunk sums (bf16 in, 16B loads) ----------------
__global__ __launch_bounds__(256)
void scan_partials(const ushort* __restrict__ ke, const ushort* __restrict__ ev,
                   float* __restrict__ pke, float* __restrict__ pkv) {
    const int H = 1024, S = 8192, CHUNK = 32, BH = 4096;
    int c  = blockIdx.x * 2 + (threadIdx.x >> 7);
    int h0 = (threadIdx.x & 127) * 8;
    int b  = blockIdx.y;
    size_t base = ((size_t)b * S + (size_t)c * CHUNK) * H + h0;
    float se[8] = {}, sv[8] = {};
    for (int s = 0; s < CHUNK; s++) {
        u16x8 e8 = *(const u16x8*)(ke + base + (size_t)s * H);
        u16x8 v8 = *(const u16x8*)(ev + base + (size_t)s * H);
        #pragma unroll
        for (int i = 0; i < 8; i++) {
            float e = bf2f(e8[i]);
            se[i] += e;
            sv[i] += e * bf2f(v8[i]);
        }
    }
    size_t p = (size_t)c * BH + b * H + h0;
    *(float4*)(pke + p)     = make_float4(se[0], se[1], se[2], se[3]);
    *(float4*)(pke + p + 4) = make_float4(se[4], se[5], se[6], se[7]);
    *(float4*)(pkv + p)     = make_float4(sv[0], sv[1], sv[2], sv[3]);
    *(float4*)(pkv + p + 4) = make_float4(sv[4], sv[5], sv[6], sv[7]);
}

// ---------------- scan pass B: exclusive prefix over chunks ----------------
__global__ __launch_bounds__(256)
void scan_offsets(float* __restrict__ pke, float* __restrict__ pkv, int nch, int BH) {
    int i = blockIdx.x * blockDim.x + threadIdx.x;
    if (i >= BH) return;
    float rke = 0.f, rkv = 0.f;
    #pragma unroll 8
    for (int c = 0; c < nch; c++) {
        size_t idx = (size_t)c * BH + i;
        float a = pke[idx], b = pkv[idx];
        pke[idx] = rke; pkv[idx] = rkv;
        rke += a; rkv += b;
    }
}

// ---------------- scan pass C: inclusive scan + y = sigmoid(emb_q)*(kv/ke) ----------------
__global__ __launch_bounds__(256)
void scan_final(const ushort* __restrict__ ke, const ushort* __restrict__ ev,
                const ushort* __restrict__ sq,
                const float* __restrict__ pke, const float* __restrict__ pkv,
                ushort* __restrict__ ybf) {
    const int H = 1024, S = 8192, CHUNK = 32, BH = 4096;
    int c  = blockIdx.x * 2 + (threadIdx.x >> 7);
    int h0 = (threadIdx.x & 127) * 8;
    int b  = blockIdx.y;
    size_t p = (size_t)c * BH + b * H + h0;
    float rke[8], rkv[8];
    *(float4*)(rke)     = *(const float4*)(pke + p);
    *(float4*)(rke + 4) = *(const float4*)(pke + p + 4);
    *(float4*)(rkv)     = *(const float4*)(pkv + p);
    *(float4*)(rkv + 4) = *(const float4*)(pkv + p + 4);
    size_t base = ((size_t)b * S + (size_t)c * CHUNK) * H + h0;
    for (int s = 0; s < CHUNK; s++) {
        size_t idx = base + (size_t)s * H;
        u16x8 e8 = *(const u16x8*)(ke + idx);
        u16x8 v8 = *(const u16x8*)(ev + idx);
        u16x8 q8 = *(const u16x8*)(sq + idx);
        u16x8 o;
        #pragma unroll
        for (int i = 0; i < 8; i++) {
            float e = bf2f(e8[i]);
            rke[i] += e;
            rkv[i] += e * bf2f(v8[i]);
            o[i] = f2bf(bf2f(q8[i]) * (rkv[i] / rke[i]));
        }
        *(u16x8*)(ybf + idx) = o;
    }
}

extern "C" void kernel_launch(void* const* d_in, const int* in_sizes, int n_in,
                              void* d_out, int out_size, void* d_ws, size_t ws_size,
                              hipStream_t stream) {
    const float* q   = (const float*)d_in[0];
    const float* k   = (const float*)d_in[1];
    const float* v   = (const float*)d_in[2];
    const float* w_q = (const float*)d_in[3];
    const float* w_k = (const float*)d_in[4];
    const float* w_v = (const float*)d_in[5];
    const float* w_p = (const float*)d_in[6];
    float* out = (float*)d_out;

    const int B = 4, S = 8192, H = 1024;
    const int M = B * S;                  // 32768
    const size_t MH = (size_t)M * H;      // 33,554,432
    const int NCH = 256;                  // CHUNK = 32
    const int BH = B * H;                 // 4096

    char* ws = (char*)d_ws;
    size_t off = 0;
    auto alloc = [&](size_t bytes) -> char* {
        char* p = ws + off;
        off += (bytes + 255) & ~(size_t)255;
        return p;
    };
    ushort* abuf = (ushort*)alloc(MH * 2);     // bf16 staging for q/k/v/y (reused serially)
    ushort* wqt  = (ushort*)alloc((size_t)H * H * 2);
    ushort* wkt  = (ushort*)alloc((size_t)H * H * 2);
    ushort* wvt  = (ushort*)alloc((size_t)H * H * 2);
    ushort* wpt  = (ushort*)alloc((size_t)H * H * 2);
    ushort* sqb  = (ushort*)alloc(MH * 2);
    ushort* keb  = (ushort*)alloc(MH * 2);
    ushort* evb  = (ushort*)alloc(MH * 2);
    float*  pke  = (float*)alloc((size_t)NCH * BH * 4);
    float*  pkv  = (float*)alloc((size_t)NCH * BH * 4);

    const int ngg = (M / 256) * (H / 256);   // 512 blocks, swizzled in-kernel
    dim3 tg(H / 32, H / 32, 4);
    dim3 gs(NCH / 2, B);
    const int n8 = (int)(MH / 8);

    transpose4_to_bf16<<<tg, 256, 0, stream>>>(w_q, w_k, w_v, w_p, wqt, wkt, wvt, wpt);

    // sq = sigmoid(q @ w_q)
    cvt_f32_bf16<<<2048, 256, 0, stream>>>((const float4*)q, (u16x8*)abuf, n8);
    gemm8p<1, 1><<<ngg, 512, 0, stream>>>(abuf, wqt, sqb);
    // ke = exp(k @ w_k)
    cvt_f32_bf16<<<2048, 256, 0, stream>>>((const float4*)k, (u16x8*)abuf, n8);
    gemm8p<2, 1><<<ngg, 512, 0, stream>>>(abuf, wkt, keb);
    // ev = v @ w_v
    cvt_f32_bf16<<<2048, 256, 0, stream>>>((const float4*)v, (u16x8*)abuf, n8);
    gemm8p<0, 1><<<ngg, 512, 0, stream>>>(abuf, wvt, evb);

    // hierarchical scan over S
    scan_partials<<<gs, 256, 0, stream>>>(keb, evb, pke, pkv);
    scan_offsets<<<BH / 256, 256, 0, stream>>>(pke, pkv, NCH, BH);
    scan_final<<<gs, 256, 0, stream>>>(keb, evb, sqb, pke, pkv, abuf);

    // out = y @ w_p (fp32 out)
    gemm8p<0, 0><<<ngg, 512, 0, stream>>>(abuf, wpt, out);
}